// Round 8
// baseline (358.857 us; speedup 1.0000x reference)
//
#include <hip/hip_runtime.h>
#include <float.h>
#include <math.h>

#define D 256
#define NROWS 65536
#define RPB 64
#define EPS_CAND 0.02f   // hi-only score error ~7 sigma (3e-3) + np quantization; candidates ~1.1/row
#define CAP 6            // max candidates per (dict,row); overflow -> full np-mimic fallback
#define WSFRAG 1024
#define ASTRIDE 520      // ushorts per (rt,s) LDS hi-fragment plane: 512 + 8 pad

// ws float layout:
//  [0..3]     alpha (float)
//  [4..963]   packed col norms ||c||^2, SEQUENTIAL UNFUSED fp32 (= numpy's axis-0 reduce)
//  [968..975] 4 doubles: per-dict loss accumulators
//  [976..983] 4 doubles: alpha fp64
//  [1024..]   dict fragments: ushort[30 tiles][16 ksteps][2 splits][64 lanes][8]

typedef __attribute__((ext_vector_type(8)))  short short8v;
typedef __attribute__((ext_vector_type(16))) float f32x16;
typedef __attribute__((ext_vector_type(4)))  float float4v;
typedef __attribute__((ext_vector_type(4)))  uint  uint4v;

__device__ __forceinline__ ushort f2bf(float v) {
    uint u = __float_as_uint(v);
    u += 0x7fffu + ((u >> 16) & 1u);
    return (ushort)(u >> 16);
}
__device__ __forceinline__ float bf2f(ushort u) { return __uint_as_float(((uint)u) << 16); }

__device__ __forceinline__ int fidx(int ct, int c, int s, int half, int j, int p) {
    return ((ct * 16 + s) * 2 + p) * 512 + (c + 32 * half) * 8 + j;   // ws (global) layout
}
__device__ __forceinline__ float dget(const ushort* fr, int pc, int d) {
    int b = fidx(pc >> 5, pc & 31, d >> 4, (d >> 3) & 1, d & 7, 0);
    return bf2f(fr[b]) + bf2f(fr[b + 512]);
}
__device__ __forceinline__ void dic_sel(int pc, const float* dc0, const float* dc1,
                                        const float* dc2, const float* dc3,
                                        const float*& dic, int& K, int& kk) {
    if      (pc < 64)  { dic = dc0; K = 64;  kk = pc;       }
    else if (pc < 192) { dic = dc1; K = 128; kk = pc - 64;  }
    else if (pc < 448) { dic = dc2; K = 256; kk = pc - 192; }
    else               { dic = dc3; K = 512; kk = pc - 448; }
}

__global__ void vq_prep(const float* __restrict__ av,
                        const float* __restrict__ dc0, const float* __restrict__ dc1,
                        const float* __restrict__ dc2, const float* __restrict__ dc3,
                        float* __restrict__ ws)
{
    int t = blockIdx.x * 256 + threadIdx.x;
    ushort* fr = (ushort*)(ws + WSFRAG);
    if (t == 0) {
        double x0 = av[0], x1 = av[1], x2 = av[2], x3 = av[3];
        double m = fmax(fmax(x0, x1), fmax(x2, x3));
        double e0 = exp(x0 - m), e1 = exp(x1 - m), e2 = exp(x2 - m), e3 = exp(x3 - m);
        double inv = 1.0 / (e0 + e1 + e2 + e3);
        ws[0] = (float)(e0 * inv); ws[1] = (float)(e1 * inv);
        ws[2] = (float)(e2 * inv); ws[3] = (float)(e3 * inv);
        double* lacc = (double*)(ws + 968);
        lacc[0] = 0.0; lacc[1] = 0.0; lacc[2] = 0.0; lacc[3] = 0.0;
        double* dal = (double*)(ws + 976);
        dal[0] = e0 * inv; dal[1] = e1 * inv; dal[2] = e2 * inv; dal[3] = e3 * inv;
    }
    if (t < 960) {   // np-exact column norms: sequential unfused fp32 (numpy axis-0 reduce)
        const float* dic; int K, kk;
        dic_sel(t, dc0, dc1, dc2, dc3, dic, K, kk);
        float s = 0.0f;
        for (int d = 0; d < D; ++d) { float v = dic[d * K + kk]; s = __fadd_rn(s, __fmul_rn(v, v)); }
        ws[4 + t] = s;
    }
    if (t < 7680) {
        int pc = t >> 3;
        const float* dic; int K, kk;
        dic_sel(pc, dc0, dc1, dc2, dc3, dic, K, kk);
        int ct = pc >> 5, c = pc & 31;
        int kb = (t & 7) * 32;
        for (int k = kb; k < kb + 32; ++k) {
            float v = dic[k * K + kk];
            ushort hu = f2bf(v);
            ushort lu = f2bf(v - bf2f(hu));
            fr[fidx(ct, c, k >> 4, (k >> 3) & 1, k & 7, 0)] = hu;
            fr[fidx(ct, c, k >> 4, (k >> 3) & 1, k & 7, 1)] = lu;
        }
    }
}

// hi-plane-only loads (p=0)
__device__ __forceinline__ void load_Bh(short8v (&B)[2], const ushort* bfr, int ct0, int s, int lane) {
#pragma unroll
    for (int cc = 0; cc < 2; ++cc)
        B[cc] = *(const short8v*)&bfr[(((ct0 + cc) * 16 + s) * 2) * 512 + lane * 8];
}
__device__ __forceinline__ void load_Ah(short8v (&A)[2], const ushort* af, int s, int lane) {
#pragma unroll
    for (int rt = 0; rt < 2; ++rt)
        A[rt] = *(const short8v*)&af[(rt * 16 + s) * ASTRIDE + lane * 8];
}

// One 2-col-tile group, hi-only scoring: 4 MFMA per kstep. emit(rt,reg,scA,scB).
// MFMA order fixed by the acc dependence chain -> bitwise identical between passes.
template<class F>
__device__ __forceinline__ void gemm_group(const ushort* af, const ushort* bfr,
                                           int ct0, int lane, float c2A, float c2B, F&& emit)
{
    f32x16 acc[2][2];
#pragma unroll
    for (int a = 0; a < 2; ++a)
#pragma unroll
        for (int b = 0; b < 2; ++b) acc[a][b] = (f32x16)(0.0f);

    short8v A[2][2], B[2][2];   // [buf][rt] / [buf][cc]
    load_Ah(A[0], af, 0, lane);
    load_Bh(B[0], bfr, ct0, 0, lane);
#pragma unroll
    for (int s = 0; s < 16; ++s) {
        if (s < 15) {
            load_Ah(A[(s + 1) & 1], af, s + 1, lane);
            load_Bh(B[(s + 1) & 1], bfr, ct0, s + 1, lane);
        }
        const int cur = s & 1;
#pragma unroll
        for (int rt = 0; rt < 2; ++rt)
#pragma unroll
            for (int cc = 0; cc < 2; ++cc)
                acc[rt][cc] = __builtin_amdgcn_mfma_f32_32x32x16_bf16(A[cur][rt], B[cur][cc], acc[rt][cc], 0, 0, 0);
    }
#pragma unroll
    for (int rt = 0; rt < 2; ++rt)
#pragma unroll
        for (int reg = 0; reg < 16; ++reg)
            emit(rt, reg, fmaf(-2.0f, acc[rt][0][reg], c2A), fmaf(-2.0f, acc[rt][1][reg], c2B));
}

__global__ void __launch_bounds__(256, 3) vq_main(
    const float* __restrict__ x,
    const float* __restrict__ dc0, const float* __restrict__ dc1,
    const float* __restrict__ dc2, const float* __restrict__ dc3,
    float* __restrict__ ws, float* __restrict__ out)
{
    __shared__ double lred[4][4];
    __shared__ __align__(16) ushort afrag[32 * ASTRIDE];   // 33280 B, hi planes only
    __shared__ float slotmin[5][64];      // pass-1 per-slot min value
    __shared__ float thrL[4][64];         // min1 + EPS_CAND
    __shared__ float f2row[64];
    __shared__ int   cnt[4][64];
    __shared__ int   cand[4][64][CAP];
    __shared__ int   kfin[4][64];
    __shared__ int   rep_list[64];
    __shared__ int   rep_cnt;

    const int tid  = threadIdx.x;
    const int lane = tid & 63;
    const int wv   = __builtin_amdgcn_readfirstlane(tid >> 6);
    const int lcol = lane & 31, half = lane >> 5;
    const size_t rowbase = (size_t)blockIdx.x * RPB;

    if (tid == 0) rep_cnt = 0;
    for (int i = tid; i < 256; i += 256) { (&cnt[0][0])[i] = 0; }

    // ---- Stage A: x -> bf16 hi fragments only (b128 writes) ----
    const float4v* x4 = (const float4v*)(x + rowbase * D);
    for (int it = 0; it < 8; ++it) {
        int f = it * 256 + tid;
        int row = f >> 5, sh = f & 31, s = sh >> 1, hf = sh & 1;
        float4v va = x4[row * 64 + s * 4 + hf * 2];
        float4v vb = x4[row * 64 + s * 4 + hf * 2 + 1];
        ushort h[8];
#pragma unroll
        for (int i = 0; i < 4; ++i) {
            h[i]     = f2bf(va[i]);
            h[4 + i] = f2bf(vb[i]);
        }
        int bu = ((row >> 5) * 16 + s) * ASTRIDE + ((row & 31) + 32 * hf) * 8;
        uint4v Hv = { (uint)h[0] | ((uint)h[1] << 16), (uint)h[2] | ((uint)h[3] << 16),
                      (uint)h[4] | ((uint)h[5] << 16), (uint)h[6] | ((uint)h[7] << 16) };
        *(uint4v*)&afrag[bu] = Hv;
    }
    __syncthreads();

    // f2 per row from exact global x (fp64 -> fp32; grid-translation makes ~1ulp variation safe)
    if (tid < 64) {
        const float* xr = x + (rowbase + tid) * D;
        double s = 0.0;
        for (int d0 = 0; d0 < D; d0 += 4) {
            float4v v = *(const float4v*)&xr[d0];
#pragma unroll
            for (int j = 0; j < 4; ++j) s = fma((double)v[j], (double)v[j], s);
        }
        f2row[tid] = (float)s;
    }

    const ushort* bfr = (const ushort*)(ws + WSFRAG);
    const float*  c2  = ws + 4;
    const int ngroups = (wv == 0) ? 3 : 4;

    // ---- pass 1: per-(dict,row) min value only ----
    {
        float rv1[2][16];
#pragma unroll
        for (int rt = 0; rt < 2; ++rt)
#pragma unroll
            for (int r = 0; r < 16; ++r) rv1[rt][r] = FLT_MAX;

        for (int g = 0; g < ngroups; ++g) {
            const int ct0 = (wv == 0) ? 2 * g : 6 + (wv - 1) * 8 + 2 * g;
            gemm_group(afrag, bfr, ct0, lane, c2[ct0 * 32 + lcol], c2[ct0 * 32 + 32 + lcol],
                [&](int rt, int reg, float sA, float sB) {
                    rv1[rt][reg] = fminf(rv1[rt][reg], fminf(sA, sB));
                });
            const bool doflush = (wv == 0) ? (g == 0 || g == 2) : (g == 3);
            if (doflush) {
                const int slot = (wv == 0) ? ((g == 0) ? 0 : 1) : wv + 1;
#pragma unroll
                for (int rt = 0; rt < 2; ++rt)
#pragma unroll
                    for (int r = 0; r < 16; ++r) {
                        float v = rv1[rt][r];
#pragma unroll
                        for (int off = 1; off <= 16; off <<= 1) v = fminf(v, __shfl_xor(v, off));
                        if (lcol == r)
                            slotmin[slot][rt * 32 + (r & 3) + 8 * (r >> 2) + 4 * half] = v;
                        rv1[rt][r] = FLT_MAX;
                    }
            }
        }
    }
    __syncthreads();

    // combine slots -> threshold
    {
        int i = tid >> 6, r = tid & 63;
        float m1 = (i < 3) ? slotmin[i][r] : fminf(slotmin[3][r], slotmin[4][r]);
        thrL[i][r] = m1 + EPS_CAND;
    }
    __syncthreads();

    // ---- pass 2: recompute scores (bitwise same), collect candidates ----
    for (int g = 0; g < ngroups; ++g) {
        const int ct0 = (wv == 0) ? 2 * g : 6 + (wv - 1) * 8 + 2 * g;
        const int dct = (wv == 0) ? ((g == 0) ? 0 : 1) : ((wv == 1) ? 2 : 3);
        gemm_group(afrag, bfr, ct0, lane, c2[ct0 * 32 + lcol], c2[ct0 * 32 + 32 + lcol],
            [&](int rt, int reg, float sA, float sB) {
                const int row = rt * 32 + (reg & 3) + 8 * (reg >> 2) + 4 * half;
                const float thr = thrL[dct][row];
                if (sA < thr) {
                    int pos = atomicAdd(&cnt[dct][row], 1);
                    if (pos < CAP) cand[dct][row][pos] = ct0 * 32 + lcol;
                }
                if (sB < thr) {
                    int pos = atomicAdd(&cnt[dct][row], 1);
                    if (pos < CAP) cand[dct][row][pos] = ct0 * 32 + 32 + lcol;
                }
            });
    }
    __syncthreads();

    // ---- final select: np-mimic among candidates (thread = (dict,row)) ----
    {
        const int i = tid >> 6, r = tid & 63;
        const int n = cnt[i][r];
        if (n > CAP) {
            int p = atomicAdd(&rep_cnt, 1);
            rep_list[p] = (i << 6) | r;
        } else {
            const float f2 = f2row[r];
            const float* xrow = x + (rowbase + r) * D;
            float best = FLT_MAX; int bi = 0x7fffffff;
            for (int j = 0; j < n; ++j) {
                const int pc = cand[i][r][j];
                double smd = 0.0;
                for (int d0 = 0; d0 < D; d0 += 8) {
                    float4v xa = *(const float4v*)&xrow[d0];
                    float4v xb = *(const float4v*)&xrow[d0 + 4];
                    int bb = fidx(pc >> 5, pc & 31, d0 >> 4, (d0 >> 3) & 1, 0, 0);
                    short8v bh = *(const short8v*)&bfr[bb];
                    short8v bl = *(const short8v*)&bfr[bb + 512];
#pragma unroll
                    for (int j2 = 0; j2 < 4; ++j2) {
                        double bv0 = (double)(bf2f((ushort)bh[j2]) + bf2f((ushort)bl[j2]));
                        double bv1 = (double)(bf2f((ushort)bh[4 + j2]) + bf2f((ushort)bl[4 + j2]));
                        smd = fma((double)xa[j2], bv0, smd);
                        smd = fma((double)xb[j2], bv1, smd);
                    }
                }
                float sim  = (float)smd;
                float dist = __fsub_rn(__fadd_rn(f2, c2[pc]), __fmul_rn(2.0f, sim));
                if (dist < best || (dist == best && pc < bi)) { best = dist; bi = pc; }
            }
            kfin[i][r] = bi;
        }
    }
    __syncthreads();

    // ---- rare fallback: full np-mimic scan (one wave per overflowed pair) ----
    for (int t = wv; t < rep_cnt; t += 4) {
        int e = rep_list[t];
        int i = e >> 6, r = e & 63;
        const float* dic; int K, base;
        if      (i == 0) { dic = dc0; K = 64;  base = 0;   }
        else if (i == 1) { dic = dc1; K = 128; base = 64;  }
        else if (i == 2) { dic = dc2; K = 256; base = 192; }
        else             { dic = dc3; K = 512; base = 448; }
        const float* xrow = x + (rowbase + r) * D;
        const float f2 = f2row[r];
        float bestv = FLT_MAX; int besti = 0x7fffffff;
        for (int c = lane; c < K; c += 64) {
            float  cn  = 0.0f;
            double smd = 0.0;
            for (int d = 0; d < D; ++d) {
                float bv = dic[d * K + c];
                cn  = __fadd_rn(cn, __fmul_rn(bv, bv));
                smd = fma((double)xrow[d], (double)bv, smd);
            }
            float sim  = (float)smd;
            float dist = __fsub_rn(__fadd_rn(f2, cn), __fmul_rn(2.0f, sim));
            if (dist < bestv) { bestv = dist; besti = c; }
        }
#pragma unroll
        for (int off = 32; off; off >>= 1) {
            float ov = __shfl_xor(bestv, off);
            int   oi = __shfl_xor(besti, off);
            if (ov < bestv || (ov == bestv && oi < besti)) { bestv = ov; besti = oi; }
        }
        if (lane == 0) kfin[i][r] = base + besti;
    }
    __syncthreads();

    // ---- epilogue: x from global (exact), q gathered hi+lo, fp64 loss ----
    const float a0 = ws[0], a1 = ws[1], a2 = ws[2], a3 = ws[3];
    double l0 = 0.0, l1 = 0.0, l2 = 0.0, l3 = 0.0;
    {
        for (int r = 0; r < RPB; ++r) {
            const float xv = x[(rowbase + r) * D + tid];
            const int i0 = kfin[0][r], i1 = kfin[1][r], i2 = kfin[2][r], i3 = kfin[3][r];
            const float q0 = dget(bfr, i0, tid);
            const float q1 = dget(bfr, i1, tid);
            const float q2 = dget(bfr, i2, tid);
            const float q3 = dget(bfr, i3, tid);
            float wq = __fadd_rn(__fadd_rn(__fadd_rn(__fmul_rn(a0, q0), __fmul_rn(a1, q1)),
                                           __fmul_rn(a2, q2)), __fmul_rn(a3, q3));
            out[(rowbase + r) * D + tid] = __fadd_rn(xv, __fsub_rn(wq, xv));
            const float e0 = xv - q0, e1 = xv - q1, e2 = xv - q2, e3 = xv - q3;
            l0 = fma((double)e0, (double)e0, l0);
            l1 = fma((double)e1, (double)e1, l1);
            l2 = fma((double)e2, (double)e2, l2);
            l3 = fma((double)e3, (double)e3, l3);
        }
    }
#pragma unroll
    for (int off = 32; off; off >>= 1) {
        l0 += __shfl_down(l0, off); l1 += __shfl_down(l1, off);
        l2 += __shfl_down(l2, off); l3 += __shfl_down(l3, off);
    }
    if (lane == 0) { lred[wv][0] = l0; lred[wv][1] = l1; lred[wv][2] = l2; lred[wv][3] = l3; }
    __syncthreads();
    if (tid == 0) {
        double* lacc = (double*)(ws + 968);
#pragma unroll
        for (int i = 0; i < 4; ++i)
            atomicAdd(lacc + i, lred[0][i] + lred[1][i] + lred[2][i] + lred[3][i]);
    }
}

__global__ void vq_fin(const float* __restrict__ ws, float* __restrict__ out)
{
    if (threadIdx.x == 0) {
        const double* lacc = (const double*)(ws + 968);
        const double* dal  = (const double*)(ws + 976);
        double s = 0.0;
#pragma unroll
        for (int i = 0; i < 4; ++i) s += (lacc[i] * (1.0 / 16777216.0)) * dal[i];
        out[16777216] = (float)(s + 0.25 * s);
    }
}

extern "C" void kernel_launch(void* const* d_in, const int* in_sizes, int n_in,
                              void* d_out, int out_size, void* d_ws, size_t ws_size,
                              hipStream_t stream)
{
    const float* x   = (const float*)d_in[0];
    const float* av  = (const float*)d_in[1];
    const float* dc0 = (const float*)d_in[2];
    const float* dc1 = (const float*)d_in[3];
    const float* dc2 = (const float*)d_in[4];
    const float* dc3 = (const float*)d_in[5];
    float* out = (float*)d_out;
    float* ws  = (float*)d_ws;

    hipLaunchKernelGGL(vq_prep, dim3(30), dim3(256), 0, stream, av, dc0, dc1, dc2, dc3, ws);
    hipLaunchKernelGGL(vq_main, dim3(NROWS / RPB), dim3(256), 0, stream,
                       x, dc0, dc1, dc2, dc3, ws, out);
    hipLaunchKernelGGL(vq_fin, dim3(1), dim3(64), 0, stream, ws, out);
}

// Round 9
// 297.393 us; speedup vs baseline: 1.2067x; 1.2067x over previous
//
#include <hip/hip_runtime.h>
#include <float.h>
#include <math.h>

#define D 256
#define NROWS 65536
#define RPB 64
#define EPS_CAND 0.02f   // hi-only score error ~7 sigma + np quantization; candidates ~1.1/row
#define CAP 6            // max candidates per (dict,row); overflow -> full np-mimic fallback
#define WSFRAG 1024
#define WSDT   246784    // float offset of plain fp32 dicT[960][256] (after fragments)
#define ASTRIDE 520      // ushorts per (rt,s) LDS hi-fragment plane: 512 + 8 pad

// ws float layout:
//  [0..3]     alpha (float)
//  [4..963]   packed col norms ||c||^2, SEQUENTIAL UNFUSED fp32 (= numpy's axis-0 reduce)
//  [968..975] 4 doubles: per-dict loss accumulators
//  [976..983] 4 doubles: alpha fp64
//  [1024..]   dict fragments: ushort[30 tiles][16 ksteps][2 splits][64 lanes][8]
//  [246784..] (optional, if ws_size permits) dicT[960][256] fp32, row = packed col

typedef __attribute__((ext_vector_type(8)))  short short8v;
typedef __attribute__((ext_vector_type(16))) float f32x16;
typedef __attribute__((ext_vector_type(4)))  float float4v;
typedef __attribute__((ext_vector_type(4)))  uint  uint4v;

__device__ __forceinline__ ushort f2bf(float v) {
    uint u = __float_as_uint(v);
    u += 0x7fffu + ((u >> 16) & 1u);
    return (ushort)(u >> 16);
}
__device__ __forceinline__ float bf2f(ushort u) { return __uint_as_float(((uint)u) << 16); }

__device__ __forceinline__ int fidx(int ct, int c, int s, int half, int j, int p) {
    return ((ct * 16 + s) * 2 + p) * 512 + (c + 32 * half) * 8 + j;   // ws (global) layout
}
__device__ __forceinline__ float dget(const ushort* fr, int pc, int d) {
    int b = fidx(pc >> 5, pc & 31, d >> 4, (d >> 3) & 1, d & 7, 0);
    return bf2f(fr[b]) + bf2f(fr[b + 512]);
}
__device__ __forceinline__ void dic_sel(int pc, const float* dc0, const float* dc1,
                                        const float* dc2, const float* dc3,
                                        const float*& dic, int& K, int& kk) {
    if      (pc < 64)  { dic = dc0; K = 64;  kk = pc;       }
    else if (pc < 192) { dic = dc1; K = 128; kk = pc - 64;  }
    else if (pc < 448) { dic = dc2; K = 256; kk = pc - 192; }
    else               { dic = dc3; K = 512; kk = pc - 448; }
}

__global__ void vq_prep(const float* __restrict__ av,
                        const float* __restrict__ dc0, const float* __restrict__ dc1,
                        const float* __restrict__ dc2, const float* __restrict__ dc3,
                        float* __restrict__ ws, float* __restrict__ dT)
{
    int t = blockIdx.x * 256 + threadIdx.x;
    ushort* fr = (ushort*)(ws + WSFRAG);
    if (t == 0) {
        double x0 = av[0], x1 = av[1], x2 = av[2], x3 = av[3];
        double m = fmax(fmax(x0, x1), fmax(x2, x3));
        double e0 = exp(x0 - m), e1 = exp(x1 - m), e2 = exp(x2 - m), e3 = exp(x3 - m);
        double inv = 1.0 / (e0 + e1 + e2 + e3);
        ws[0] = (float)(e0 * inv); ws[1] = (float)(e1 * inv);
        ws[2] = (float)(e2 * inv); ws[3] = (float)(e3 * inv);
        double* lacc = (double*)(ws + 968);
        lacc[0] = 0.0; lacc[1] = 0.0; lacc[2] = 0.0; lacc[3] = 0.0;
        double* dal = (double*)(ws + 976);
        dal[0] = e0 * inv; dal[1] = e1 * inv; dal[2] = e2 * inv; dal[3] = e3 * inv;
    }
    if (t < 960) {   // np-exact column norms (sequential unfused fp32) + plain fp32 transposed copy
        const float* dic; int K, kk;
        dic_sel(t, dc0, dc1, dc2, dc3, dic, K, kk);
        float s = 0.0f;
        if (dT != nullptr) {
            float* dr = dT + (size_t)t * D;
            for (int d = 0; d < D; ++d) {
                float v = dic[d * K + kk];
                s = __fadd_rn(s, __fmul_rn(v, v));
                dr[d] = v;
            }
        } else {
            for (int d = 0; d < D; ++d) {
                float v = dic[d * K + kk];
                s = __fadd_rn(s, __fmul_rn(v, v));
            }
        }
        ws[4 + t] = s;
    }
    if (t < 7680) {
        int pc = t >> 3;
        const float* dic; int K, kk;
        dic_sel(pc, dc0, dc1, dc2, dc3, dic, K, kk);
        int ct = pc >> 5, c = pc & 31;
        int kb = (t & 7) * 32;
        for (int k = kb; k < kb + 32; ++k) {
            float v = dic[k * K + kk];
            ushort hu = f2bf(v);
            ushort lu = f2bf(v - bf2f(hu));
            fr[fidx(ct, c, k >> 4, (k >> 3) & 1, k & 7, 0)] = hu;
            fr[fidx(ct, c, k >> 4, (k >> 3) & 1, k & 7, 1)] = lu;
        }
    }
}

// hi-plane-only loads (p=0)
__device__ __forceinline__ void load_Bh(short8v (&B)[2], const ushort* bfr, int ct0, int s, int lane) {
#pragma unroll
    for (int cc = 0; cc < 2; ++cc)
        B[cc] = *(const short8v*)&bfr[(((ct0 + cc) * 16 + s) * 2) * 512 + lane * 8];
}
__device__ __forceinline__ void load_Ah(short8v (&A)[2], const ushort* af, int s, int lane) {
#pragma unroll
    for (int rt = 0; rt < 2; ++rt)
        A[rt] = *(const short8v*)&af[(rt * 16 + s) * ASTRIDE + lane * 8];
}

// One 2-col-tile group, hi-only scoring: 4 MFMA per kstep. emit(rt,reg,scA,scB).
// MFMA order fixed by the acc dependence chain -> bitwise identical between passes.
template<class F>
__device__ __forceinline__ void gemm_group(const ushort* af, const ushort* bfr,
                                           int ct0, int lane, float c2A, float c2B, F&& emit)
{
    f32x16 acc[2][2];
#pragma unroll
    for (int a = 0; a < 2; ++a)
#pragma unroll
        for (int b = 0; b < 2; ++b) acc[a][b] = (f32x16)(0.0f);

    short8v A[2][2], B[2][2];   // [buf][rt] / [buf][cc]
    load_Ah(A[0], af, 0, lane);
    load_Bh(B[0], bfr, ct0, 0, lane);
#pragma unroll
    for (int s = 0; s < 16; ++s) {
        if (s < 15) {
            load_Ah(A[(s + 1) & 1], af, s + 1, lane);
            load_Bh(B[(s + 1) & 1], bfr, ct0, s + 1, lane);
        }
        const int cur = s & 1;
#pragma unroll
        for (int rt = 0; rt < 2; ++rt)
#pragma unroll
            for (int cc = 0; cc < 2; ++cc)
                acc[rt][cc] = __builtin_amdgcn_mfma_f32_32x32x16_bf16(A[cur][rt], B[cur][cc], acc[rt][cc], 0, 0, 0);
    }
#pragma unroll
    for (int rt = 0; rt < 2; ++rt)
#pragma unroll
        for (int reg = 0; reg < 16; ++reg)
            emit(rt, reg, fmaf(-2.0f, acc[rt][0][reg], c2A), fmaf(-2.0f, acc[rt][1][reg], c2B));
}

__global__ void __launch_bounds__(256, 2) vq_main(
    const float* __restrict__ x,
    const float* __restrict__ dc0, const float* __restrict__ dc1,
    const float* __restrict__ dc2, const float* __restrict__ dc3,
    float* __restrict__ ws, const float* __restrict__ dT, float* __restrict__ out)
{
    __shared__ double lred[4][4];
    __shared__ __align__(16) ushort afrag[32 * ASTRIDE];   // 33280 B, hi planes only
    __shared__ float slotmin[5][64];      // pass-1 per-slot min value
    __shared__ float thrL[4][64];         // min1 + EPS_CAND
    __shared__ float f2row[64];
    __shared__ int   cnt[4][64];
    __shared__ int   cand[4][64][CAP];
    __shared__ int   kfin[4][64];
    __shared__ int   rep_list[64];
    __shared__ int   rep_cnt;

    const int tid  = threadIdx.x;
    const int lane = tid & 63;
    const int wv   = __builtin_amdgcn_readfirstlane(tid >> 6);
    const int lcol = lane & 31, half = lane >> 5;
    const size_t rowbase = (size_t)blockIdx.x * RPB;

    if (tid == 0) rep_cnt = 0;
    for (int i = tid; i < 256; i += 256) { (&cnt[0][0])[i] = 0; }

    // ---- Stage A: x -> bf16 hi fragments only (b128 writes) ----
    const float4v* x4 = (const float4v*)(x + rowbase * D);
    for (int it = 0; it < 8; ++it) {
        int f = it * 256 + tid;
        int row = f >> 5, sh = f & 31, s = sh >> 1, hf = sh & 1;
        float4v va = x4[row * 64 + s * 4 + hf * 2];
        float4v vb = x4[row * 64 + s * 4 + hf * 2 + 1];
        ushort h[8];
#pragma unroll
        for (int i = 0; i < 4; ++i) {
            h[i]     = f2bf(va[i]);
            h[4 + i] = f2bf(vb[i]);
        }
        int bu = ((row >> 5) * 16 + s) * ASTRIDE + ((row & 31) + 32 * hf) * 8;
        uint4v Hv = { (uint)h[0] | ((uint)h[1] << 16), (uint)h[2] | ((uint)h[3] << 16),
                      (uint)h[4] | ((uint)h[5] << 16), (uint)h[6] | ((uint)h[7] << 16) };
        *(uint4v*)&afrag[bu] = Hv;
    }
    __syncthreads();

    // f2 per row from exact global x (fp64 -> fp32)
    if (tid < 64) {
        const float* xr = x + (rowbase + tid) * D;
        double s = 0.0;
        for (int d0 = 0; d0 < D; d0 += 4) {
            float4v v = *(const float4v*)&xr[d0];
#pragma unroll
            for (int j = 0; j < 4; ++j) s = fma((double)v[j], (double)v[j], s);
        }
        f2row[tid] = (float)s;
    }

    const ushort* bfr = (const ushort*)(ws + WSFRAG);
    const float*  c2  = ws + 4;
    const int ngroups = (wv == 0) ? 3 : 4;

    // ---- pass 1: per-(dict,row) min value only ----
    {
        float rv1[2][16];
#pragma unroll
        for (int rt = 0; rt < 2; ++rt)
#pragma unroll
            for (int r = 0; r < 16; ++r) rv1[rt][r] = FLT_MAX;

        for (int g = 0; g < ngroups; ++g) {
            const int ct0 = (wv == 0) ? 2 * g : 6 + (wv - 1) * 8 + 2 * g;
            gemm_group(afrag, bfr, ct0, lane, c2[ct0 * 32 + lcol], c2[ct0 * 32 + 32 + lcol],
                [&](int rt, int reg, float sA, float sB) {
                    rv1[rt][reg] = fminf(rv1[rt][reg], fminf(sA, sB));
                });
            const bool doflush = (wv == 0) ? (g == 0 || g == 2) : (g == 3);
            if (doflush) {
                const int slot = (wv == 0) ? ((g == 0) ? 0 : 1) : wv + 1;
#pragma unroll
                for (int rt = 0; rt < 2; ++rt)
#pragma unroll
                    for (int r = 0; r < 16; ++r) {
                        float v = rv1[rt][r];
#pragma unroll
                        for (int off = 1; off <= 16; off <<= 1) v = fminf(v, __shfl_xor(v, off));
                        if (lcol == r)
                            slotmin[slot][rt * 32 + (r & 3) + 8 * (r >> 2) + 4 * half] = v;
                        rv1[rt][r] = FLT_MAX;
                    }
            }
        }
    }
    __syncthreads();

    // combine slots -> threshold
    {
        int i = tid >> 6, r = tid & 63;
        float m1 = (i < 3) ? slotmin[i][r] : fminf(slotmin[3][r], slotmin[4][r]);
        thrL[i][r] = m1 + EPS_CAND;
    }
    __syncthreads();

    // ---- pass 2: recompute scores (bitwise same), collect candidates ----
    for (int g = 0; g < ngroups; ++g) {
        const int ct0 = (wv == 0) ? 2 * g : 6 + (wv - 1) * 8 + 2 * g;
        const int dct = (wv == 0) ? ((g == 0) ? 0 : 1) : ((wv == 1) ? 2 : 3);
        gemm_group(afrag, bfr, ct0, lane, c2[ct0 * 32 + lcol], c2[ct0 * 32 + 32 + lcol],
            [&](int rt, int reg, float sA, float sB) {
                const int row = rt * 32 + (reg & 3) + 8 * (reg >> 2) + 4 * half;
                const float thr = thrL[dct][row];
                if (sA < thr) {
                    int pos = atomicAdd(&cnt[dct][row], 1);
                    if (pos < CAP) cand[dct][row][pos] = ct0 * 32 + lcol;
                }
                if (sB < thr) {
                    int pos = atomicAdd(&cnt[dct][row], 1);
                    if (pos < CAP) cand[dct][row][pos] = ct0 * 32 + 32 + lcol;
                }
            });
    }
    __syncthreads();

    // ---- final select: np-mimic among candidates (thread = (dict,row)) ----
    {
        const int i = tid >> 6, r = tid & 63;
        const int n = cnt[i][r];
        if (n > CAP) {
            int p = atomicAdd(&rep_cnt, 1);
            rep_list[p] = (i << 6) | r;
        } else {
            const float f2 = f2row[r];
            const float* xrow = x + (rowbase + r) * D;
            float best = FLT_MAX; int bi = 0x7fffffff;
            for (int j = 0; j < n; ++j) {
                const int pc = cand[i][r][j];
                double smd = 0.0;
                if (dT != nullptr) {
                    const float* br = dT + (size_t)pc * D;
                    for (int d0 = 0; d0 < D; d0 += 4) {
                        float4v xa = *(const float4v*)&xrow[d0];
                        float4v bb = *(const float4v*)&br[d0];
#pragma unroll
                        for (int j2 = 0; j2 < 4; ++j2)
                            smd = fma((double)xa[j2], (double)bb[j2], smd);
                    }
                } else {
                    for (int d0 = 0; d0 < D; d0 += 8) {
                        float4v xa = *(const float4v*)&xrow[d0];
                        float4v xb = *(const float4v*)&xrow[d0 + 4];
                        int bb = fidx(pc >> 5, pc & 31, d0 >> 4, (d0 >> 3) & 1, 0, 0);
                        short8v bh = *(const short8v*)&bfr[bb];
                        short8v bl = *(const short8v*)&bfr[bb + 512];
#pragma unroll
                        for (int j2 = 0; j2 < 4; ++j2) {
                            double bv0 = (double)(bf2f((ushort)bh[j2]) + bf2f((ushort)bl[j2]));
                            double bv1 = (double)(bf2f((ushort)bh[4 + j2]) + bf2f((ushort)bl[4 + j2]));
                            smd = fma((double)xa[j2], bv0, smd);
                            smd = fma((double)xb[j2], bv1, smd);
                        }
                    }
                }
                float sim  = (float)smd;
                float dist = __fsub_rn(__fadd_rn(f2, c2[pc]), __fmul_rn(2.0f, sim));
                if (dist < best || (dist == best && pc < bi)) { best = dist; bi = pc; }
            }
            kfin[i][r] = bi;
        }
    }
    __syncthreads();

    // ---- rare fallback: full np-mimic scan (one wave per overflowed pair) ----
    for (int t = wv; t < rep_cnt; t += 4) {
        int e = rep_list[t];
        int i = e >> 6, r = e & 63;
        const float* dic; int K, base;
        if      (i == 0) { dic = dc0; K = 64;  base = 0;   }
        else if (i == 1) { dic = dc1; K = 128; base = 64;  }
        else if (i == 2) { dic = dc2; K = 256; base = 192; }
        else             { dic = dc3; K = 512; base = 448; }
        const float* xrow = x + (rowbase + r) * D;
        const float f2 = f2row[r];
        float bestv = FLT_MAX; int besti = 0x7fffffff;
        for (int c = lane; c < K; c += 64) {
            float  cn  = 0.0f;
            double smd = 0.0;
            for (int d = 0; d < D; ++d) {
                float bv = dic[d * K + c];
                cn  = __fadd_rn(cn, __fmul_rn(bv, bv));
                smd = fma((double)xrow[d], (double)bv, smd);
            }
            float sim  = (float)smd;
            float dist = __fsub_rn(__fadd_rn(f2, cn), __fmul_rn(2.0f, sim));
            if (dist < bestv) { bestv = dist; besti = c; }
        }
#pragma unroll
        for (int off = 32; off; off >>= 1) {
            float ov = __shfl_xor(bestv, off);
            int   oi = __shfl_xor(besti, off);
            if (ov < bestv || (ov == bestv && oi < besti)) { bestv = ov; besti = oi; }
        }
        if (lane == 0) kfin[i][r] = base + besti;
    }
    __syncthreads();

    // ---- epilogue: x from global, q from plain dicT (coalesced) or fragments, fp64 loss ----
    const float a0 = ws[0], a1 = ws[1], a2 = ws[2], a3 = ws[3];
    double l0 = 0.0, l1 = 0.0, l2 = 0.0, l3 = 0.0;
    for (int r = 0; r < RPB; ++r) {
        const float xv = x[(rowbase + r) * D + tid];
        const int i0 = kfin[0][r], i1 = kfin[1][r], i2 = kfin[2][r], i3 = kfin[3][r];
        float q0, q1, q2, q3;
        if (dT != nullptr) {
            q0 = dT[(size_t)i0 * D + tid];
            q1 = dT[(size_t)i1 * D + tid];
            q2 = dT[(size_t)i2 * D + tid];
            q3 = dT[(size_t)i3 * D + tid];
        } else {
            q0 = dget(bfr, i0, tid);
            q1 = dget(bfr, i1, tid);
            q2 = dget(bfr, i2, tid);
            q3 = dget(bfr, i3, tid);
        }
        float wq = __fadd_rn(__fadd_rn(__fadd_rn(__fmul_rn(a0, q0), __fmul_rn(a1, q1)),
                                       __fmul_rn(a2, q2)), __fmul_rn(a3, q3));
        out[(rowbase + r) * D + tid] = __fadd_rn(xv, __fsub_rn(wq, xv));
        const float e0 = xv - q0, e1 = xv - q1, e2 = xv - q2, e3 = xv - q3;
        l0 = fma((double)e0, (double)e0, l0);
        l1 = fma((double)e1, (double)e1, l1);
        l2 = fma((double)e2, (double)e2, l2);
        l3 = fma((double)e3, (double)e3, l3);
    }
#pragma unroll
    for (int off = 32; off; off >>= 1) {
        l0 += __shfl_down(l0, off); l1 += __shfl_down(l1, off);
        l2 += __shfl_down(l2, off); l3 += __shfl_down(l3, off);
    }
    if (lane == 0) { lred[wv][0] = l0; lred[wv][1] = l1; lred[wv][2] = l2; lred[wv][3] = l3; }
    __syncthreads();
    if (tid == 0) {
        double* lacc = (double*)(ws + 968);
#pragma unroll
        for (int i = 0; i < 4; ++i)
            atomicAdd(lacc + i, lred[0][i] + lred[1][i] + lred[2][i] + lred[3][i]);
    }
}

__global__ void vq_fin(const float* __restrict__ ws, float* __restrict__ out)
{
    if (threadIdx.x == 0) {
        const double* lacc = (const double*)(ws + 968);
        const double* dal  = (const double*)(ws + 976);
        double s = 0.0;
#pragma unroll
        for (int i = 0; i < 4; ++i) s += (lacc[i] * (1.0 / 16777216.0)) * dal[i];
        out[16777216] = (float)(s + 0.25 * s);
    }
}

extern "C" void kernel_launch(void* const* d_in, const int* in_sizes, int n_in,
                              void* d_out, int out_size, void* d_ws, size_t ws_size,
                              hipStream_t stream)
{
    const float* x   = (const float*)d_in[0];
    const float* av  = (const float*)d_in[1];
    const float* dc0 = (const float*)d_in[2];
    const float* dc1 = (const float*)d_in[3];
    const float* dc2 = (const float*)d_in[4];
    const float* dc3 = (const float*)d_in[5];
    float* out = (float*)d_out;
    float* ws  = (float*)d_ws;

    // plain fp32 dicT copy needs ws to hold 246784 + 960*256 floats
    const bool haveDT = ws_size >= (size_t)(WSDT + 960 * 256) * sizeof(float);
    float* dT = haveDT ? (ws + WSDT) : nullptr;

    hipLaunchKernelGGL(vq_prep, dim3(30), dim3(256), 0, stream, av, dc0, dc1, dc2, dc3, ws, dT);
    hipLaunchKernelGGL(vq_main, dim3(NROWS / RPB), dim3(256), 0, stream,
                       x, dc0, dc1, dc2, dc3, ws, dT, out);
    hipLaunchKernelGGL(vq_fin, dim3(1), dim3(64), 0, stream, ws, out);
}

// Round 10
// 282.187 us; speedup vs baseline: 1.2717x; 1.0539x over previous
//
#include <hip/hip_runtime.h>
#include <float.h>
#include <math.h>

#define D 256
#define NROWS 65536
#define RPB 64
#define EPS_CAND 0.02f   // hi-only score error ~7 sigma + np quantization; candidates ~1.1/row
#define CAP 6            // max candidates per (dict,row); overflow -> full np-mimic fallback
#define WSFRAG 1024
#define WSDT   246784    // float offset of plain fp32 dicT[960][256] (after fragments)
#define ASTRIDE 520      // ushorts per (rt,s) LDS hi-fragment plane: 512 + 8 pad

// ws float layout:
//  [0..3]     alpha (float)
//  [4..963]   packed col norms ||c||^2, SEQUENTIAL UNFUSED fp32 (= numpy's axis-0 reduce)
//  [968..975] 4 doubles: per-dict loss accumulators
//  [976..983] 4 doubles: alpha fp64
//  [1024..]   dict fragments: ushort[30 tiles][16 ksteps][2 splits][64 lanes][8]
//  [246784..] (optional, if ws_size permits) dicT[960][256] fp32, row = packed col

typedef __attribute__((ext_vector_type(8)))  short short8v;
typedef __attribute__((ext_vector_type(16))) float f32x16;
typedef __attribute__((ext_vector_type(4)))  float float4v;
typedef __attribute__((ext_vector_type(4)))  uint  uint4v;

__device__ __forceinline__ ushort f2bf(float v) {
    uint u = __float_as_uint(v);
    u += 0x7fffu + ((u >> 16) & 1u);
    return (ushort)(u >> 16);
}
__device__ __forceinline__ float bf2f(ushort u) { return __uint_as_float(((uint)u) << 16); }

__device__ __forceinline__ int fidx(int ct, int c, int s, int half, int j, int p) {
    return ((ct * 16 + s) * 2 + p) * 512 + (c + 32 * half) * 8 + j;   // ws (global) layout
}
__device__ __forceinline__ float dget(const ushort* fr, int pc, int d) {
    int b = fidx(pc >> 5, pc & 31, d >> 4, (d >> 3) & 1, d & 7, 0);
    return bf2f(fr[b]) + bf2f(fr[b + 512]);
}
__device__ __forceinline__ void dic_sel(int pc, const float* dc0, const float* dc1,
                                        const float* dc2, const float* dc3,
                                        const float*& dic, int& K, int& kk) {
    if      (pc < 64)  { dic = dc0; K = 64;  kk = pc;       }
    else if (pc < 192) { dic = dc1; K = 128; kk = pc - 64;  }
    else if (pc < 448) { dic = dc2; K = 256; kk = pc - 192; }
    else               { dic = dc3; K = 512; kk = pc - 448; }
}

__global__ void vq_prep(const float* __restrict__ av,
                        const float* __restrict__ dc0, const float* __restrict__ dc1,
                        const float* __restrict__ dc2, const float* __restrict__ dc3,
                        float* __restrict__ ws, float* __restrict__ dT)
{
    int t = blockIdx.x * 256 + threadIdx.x;
    ushort* fr = (ushort*)(ws + WSFRAG);
    if (t == 0) {
        double x0 = av[0], x1 = av[1], x2 = av[2], x3 = av[3];
        double m = fmax(fmax(x0, x1), fmax(x2, x3));
        double e0 = exp(x0 - m), e1 = exp(x1 - m), e2 = exp(x2 - m), e3 = exp(x3 - m);
        double inv = 1.0 / (e0 + e1 + e2 + e3);
        ws[0] = (float)(e0 * inv); ws[1] = (float)(e1 * inv);
        ws[2] = (float)(e2 * inv); ws[3] = (float)(e3 * inv);
        double* lacc = (double*)(ws + 968);
        lacc[0] = 0.0; lacc[1] = 0.0; lacc[2] = 0.0; lacc[3] = 0.0;
        double* dal = (double*)(ws + 976);
        dal[0] = e0 * inv; dal[1] = e1 * inv; dal[2] = e2 * inv; dal[3] = e3 * inv;
    }
    if (t < 960) {   // np-exact column norms (sequential unfused fp32) + plain fp32 transposed copy
        const float* dic; int K, kk;
        dic_sel(t, dc0, dc1, dc2, dc3, dic, K, kk);
        float s = 0.0f;
        if (dT != nullptr) {
            float* dr = dT + (size_t)t * D;
            for (int d = 0; d < D; ++d) {
                float v = dic[d * K + kk];
                s = __fadd_rn(s, __fmul_rn(v, v));
                dr[d] = v;
            }
        } else {
            for (int d = 0; d < D; ++d) {
                float v = dic[d * K + kk];
                s = __fadd_rn(s, __fmul_rn(v, v));
            }
        }
        ws[4 + t] = s;
    }
    if (t < 7680) {
        int pc = t >> 3;
        const float* dic; int K, kk;
        dic_sel(pc, dc0, dc1, dc2, dc3, dic, K, kk);
        int ct = pc >> 5, c = pc & 31;
        int kb = (t & 7) * 32;
        for (int k = kb; k < kb + 32; ++k) {
            float v = dic[k * K + kk];
            ushort hu = f2bf(v);
            ushort lu = f2bf(v - bf2f(hu));
            fr[fidx(ct, c, k >> 4, (k >> 3) & 1, k & 7, 0)] = hu;
            fr[fidx(ct, c, k >> 4, (k >> 3) & 1, k & 7, 1)] = lu;
        }
    }
}

// hi-plane-only loads (p=0)
__device__ __forceinline__ void load_Bh(short8v (&B)[2], const ushort* bfr, int ct0, int s, int lane) {
#pragma unroll
    for (int cc = 0; cc < 2; ++cc)
        B[cc] = *(const short8v*)&bfr[(((ct0 + cc) * 16 + s) * 2) * 512 + lane * 8];
}
__device__ __forceinline__ void load_Ah(short8v (&A)[2], const ushort* af, int s, int lane) {
#pragma unroll
    for (int rt = 0; rt < 2; ++rt)
        A[rt] = *(const short8v*)&af[(rt * 16 + s) * ASTRIDE + lane * 8];
}

// One 2-col-tile group, hi-only scoring: 4 MFMA per kstep, B prefetched 3 ksteps ahead
// (4 buffers) to cover ~200cy L2 latency with ~3 ksteps of MFMA. emit(rt,reg,scA,scB).
// MFMA order fixed by the acc dependence chain -> bitwise identical between passes.
template<class F>
__device__ __forceinline__ void gemm_group(const ushort* af, const ushort* bfr,
                                           int ct0, int lane, float c2A, float c2B, F&& emit)
{
    f32x16 acc[2][2];
#pragma unroll
    for (int a = 0; a < 2; ++a)
#pragma unroll
        for (int b = 0; b < 2; ++b) acc[a][b] = (f32x16)(0.0f);

    short8v A[2][2], B[4][2];   // A: [buf][rt] 2-deep (LDS), B: [buf][cc] 4-deep (global/L2)
    load_Ah(A[0], af, 0, lane);
    load_Bh(B[0], bfr, ct0, 0, lane);
    load_Bh(B[1], bfr, ct0, 1, lane);
    load_Bh(B[2], bfr, ct0, 2, lane);
#pragma unroll
    for (int s = 0; s < 16; ++s) {
        if (s < 13) load_Bh(B[(s + 3) & 3], bfr, ct0, s + 3, lane);
        if (s < 15) load_Ah(A[(s + 1) & 1], af, s + 1, lane);
        const int ai = s & 1, bi = s & 3;
#pragma unroll
        for (int rt = 0; rt < 2; ++rt)
#pragma unroll
            for (int cc = 0; cc < 2; ++cc)
                acc[rt][cc] = __builtin_amdgcn_mfma_f32_32x32x16_bf16(A[ai][rt], B[bi][cc], acc[rt][cc], 0, 0, 0);
    }
#pragma unroll
    for (int rt = 0; rt < 2; ++rt)
#pragma unroll
        for (int reg = 0; reg < 16; ++reg)
            emit(rt, reg, fmaf(-2.0f, acc[rt][0][reg], c2A), fmaf(-2.0f, acc[rt][1][reg], c2B));
}

__global__ void __launch_bounds__(256, 2) vq_main(
    const float* __restrict__ x,
    const float* __restrict__ dc0, const float* __restrict__ dc1,
    const float* __restrict__ dc2, const float* __restrict__ dc3,
    float* __restrict__ ws, const float* __restrict__ dT, float* __restrict__ out)
{
    __shared__ double lred[4][4];
    __shared__ __align__(16) ushort afrag[32 * ASTRIDE];   // 33280 B, hi planes only
    __shared__ float slotmin[5][64];      // pass-1 per-slot min value
    __shared__ float thrL[4][64];         // min1 + EPS_CAND
    __shared__ float f2row[64];
    __shared__ int   cnt[4][64];
    __shared__ int   cand[4][64][CAP];
    __shared__ int   kfin[4][64];
    __shared__ int   rep_list[64];
    __shared__ int   rep_cnt;

    const int tid  = threadIdx.x;
    const int lane = tid & 63;
    const int wv   = __builtin_amdgcn_readfirstlane(tid >> 6);
    const int lcol = lane & 31, half = lane >> 5;
    const size_t rowbase = (size_t)blockIdx.x * RPB;

    if (tid == 0) rep_cnt = 0;
    for (int i = tid; i < 256; i += 256) { (&cnt[0][0])[i] = 0; }

    // ---- Stage A: x -> bf16 hi fragments only (b128 writes) ----
    const float4v* x4 = (const float4v*)(x + rowbase * D);
    for (int it = 0; it < 8; ++it) {
        int f = it * 256 + tid;
        int row = f >> 5, sh = f & 31, s = sh >> 1, hf = sh & 1;
        float4v va = x4[row * 64 + s * 4 + hf * 2];
        float4v vb = x4[row * 64 + s * 4 + hf * 2 + 1];
        ushort h[8];
#pragma unroll
        for (int i = 0; i < 4; ++i) {
            h[i]     = f2bf(va[i]);
            h[4 + i] = f2bf(vb[i]);
        }
        int bu = ((row >> 5) * 16 + s) * ASTRIDE + ((row & 31) + 32 * hf) * 8;
        uint4v Hv = { (uint)h[0] | ((uint)h[1] << 16), (uint)h[2] | ((uint)h[3] << 16),
                      (uint)h[4] | ((uint)h[5] << 16), (uint)h[6] | ((uint)h[7] << 16) };
        *(uint4v*)&afrag[bu] = Hv;
    }
    __syncthreads();

    // f2 per row from exact global x (fp64 -> fp32)
    if (tid < 64) {
        const float* xr = x + (rowbase + tid) * D;
        double s = 0.0;
        for (int d0 = 0; d0 < D; d0 += 4) {
            float4v v = *(const float4v*)&xr[d0];
#pragma unroll
            for (int j = 0; j < 4; ++j) s = fma((double)v[j], (double)v[j], s);
        }
        f2row[tid] = (float)s;
    }

    const ushort* bfr = (const ushort*)(ws + WSFRAG);
    const float*  c2  = ws + 4;
    const int ngroups = (wv == 0) ? 3 : 4;

    // ---- pass 1: per-(dict,row) min value only ----
    {
        float rv1[2][16];
#pragma unroll
        for (int rt = 0; rt < 2; ++rt)
#pragma unroll
            for (int r = 0; r < 16; ++r) rv1[rt][r] = FLT_MAX;

        for (int g = 0; g < ngroups; ++g) {
            const int ct0 = (wv == 0) ? 2 * g : 6 + (wv - 1) * 8 + 2 * g;
            gemm_group(afrag, bfr, ct0, lane, c2[ct0 * 32 + lcol], c2[ct0 * 32 + 32 + lcol],
                [&](int rt, int reg, float sA, float sB) {
                    rv1[rt][reg] = fminf(rv1[rt][reg], fminf(sA, sB));
                });
            const bool doflush = (wv == 0) ? (g == 0 || g == 2) : (g == 3);
            if (doflush) {
                const int slot = (wv == 0) ? ((g == 0) ? 0 : 1) : wv + 1;
#pragma unroll
                for (int rt = 0; rt < 2; ++rt)
#pragma unroll
                    for (int r = 0; r < 16; ++r) {
                        float v = rv1[rt][r];
#pragma unroll
                        for (int off = 1; off <= 16; off <<= 1) v = fminf(v, __shfl_xor(v, off));
                        if (lcol == r)
                            slotmin[slot][rt * 32 + (r & 3) + 8 * (r >> 2) + 4 * half] = v;
                        rv1[rt][r] = FLT_MAX;
                    }
            }
        }
    }
    __syncthreads();

    // combine slots -> threshold
    {
        int i = tid >> 6, r = tid & 63;
        float m1 = (i < 3) ? slotmin[i][r] : fminf(slotmin[3][r], slotmin[4][r]);
        thrL[i][r] = m1 + EPS_CAND;
    }
    __syncthreads();

    // ---- pass 2: recompute scores (bitwise same), collect candidates ----
    for (int g = 0; g < ngroups; ++g) {
        const int ct0 = (wv == 0) ? 2 * g : 6 + (wv - 1) * 8 + 2 * g;
        const int dct = (wv == 0) ? ((g == 0) ? 0 : 1) : ((wv == 1) ? 2 : 3);
        gemm_group(afrag, bfr, ct0, lane, c2[ct0 * 32 + lcol], c2[ct0 * 32 + 32 + lcol],
            [&](int rt, int reg, float sA, float sB) {
                const int row = rt * 32 + (reg & 3) + 8 * (reg >> 2) + 4 * half;
                const float thr = thrL[dct][row];
                if (sA < thr) {
                    int pos = atomicAdd(&cnt[dct][row], 1);
                    if (pos < CAP) cand[dct][row][pos] = ct0 * 32 + lcol;
                }
                if (sB < thr) {
                    int pos = atomicAdd(&cnt[dct][row], 1);
                    if (pos < CAP) cand[dct][row][pos] = ct0 * 32 + 32 + lcol;
                }
            });
    }
    __syncthreads();

    // ---- final select: np-mimic among candidates (thread = (dict,row)) ----
    {
        const int i = tid >> 6, r = tid & 63;
        const int n = cnt[i][r];
        if (n > CAP) {
            int p = atomicAdd(&rep_cnt, 1);
            rep_list[p] = (i << 6) | r;
        } else {
            const float f2 = f2row[r];
            const float* xrow = x + (rowbase + r) * D;
            float best = FLT_MAX; int bi = 0x7fffffff;
            for (int j = 0; j < n; ++j) {
                const int pc = cand[i][r][j];
                double smd = 0.0;
                if (dT != nullptr) {
                    const float* br = dT + (size_t)pc * D;
                    for (int d0 = 0; d0 < D; d0 += 4) {
                        float4v xa = *(const float4v*)&xrow[d0];
                        float4v bb = *(const float4v*)&br[d0];
#pragma unroll
                        for (int j2 = 0; j2 < 4; ++j2)
                            smd = fma((double)xa[j2], (double)bb[j2], smd);
                    }
                } else {
                    for (int d0 = 0; d0 < D; d0 += 8) {
                        float4v xa = *(const float4v*)&xrow[d0];
                        float4v xb = *(const float4v*)&xrow[d0 + 4];
                        int bb = fidx(pc >> 5, pc & 31, d0 >> 4, (d0 >> 3) & 1, 0, 0);
                        short8v bh = *(const short8v*)&bfr[bb];
                        short8v bl = *(const short8v*)&bfr[bb + 512];
#pragma unroll
                        for (int j2 = 0; j2 < 4; ++j2) {
                            double bv0 = (double)(bf2f((ushort)bh[j2]) + bf2f((ushort)bl[j2]));
                            double bv1 = (double)(bf2f((ushort)bh[4 + j2]) + bf2f((ushort)bl[4 + j2]));
                            smd = fma((double)xa[j2], bv0, smd);
                            smd = fma((double)xb[j2], bv1, smd);
                        }
                    }
                }
                float sim  = (float)smd;
                float dist = __fsub_rn(__fadd_rn(f2, c2[pc]), __fmul_rn(2.0f, sim));
                if (dist < best || (dist == best && pc < bi)) { best = dist; bi = pc; }
            }
            kfin[i][r] = bi;
        }
    }
    __syncthreads();

    // ---- rare fallback: full np-mimic scan (one wave per overflowed pair) ----
    for (int t = wv; t < rep_cnt; t += 4) {
        int e = rep_list[t];
        int i = e >> 6, r = e & 63;
        const float* dic; int K, base;
        if      (i == 0) { dic = dc0; K = 64;  base = 0;   }
        else if (i == 1) { dic = dc1; K = 128; base = 64;  }
        else if (i == 2) { dic = dc2; K = 256; base = 192; }
        else             { dic = dc3; K = 512; base = 448; }
        const float* xrow = x + (rowbase + r) * D;
        const float f2 = f2row[r];
        float bestv = FLT_MAX; int besti = 0x7fffffff;
        for (int c = lane; c < K; c += 64) {
            float  cn  = 0.0f;
            double smd = 0.0;
            for (int d = 0; d < D; ++d) {
                float bv = dic[d * K + c];
                cn  = __fadd_rn(cn, __fmul_rn(bv, bv));
                smd = fma((double)xrow[d], (double)bv, smd);
            }
            float sim  = (float)smd;
            float dist = __fsub_rn(__fadd_rn(f2, cn), __fmul_rn(2.0f, sim));
            if (dist < bestv) { bestv = dist; besti = c; }
        }
#pragma unroll
        for (int off = 32; off; off >>= 1) {
            float ov = __shfl_xor(bestv, off);
            int   oi = __shfl_xor(besti, off);
            if (ov < bestv || (ov == bestv && oi < besti)) { bestv = ov; besti = oi; }
        }
        if (lane == 0) kfin[i][r] = base + besti;
    }
    __syncthreads();

    // ---- epilogue: x from global, q from plain dicT (coalesced) or fragments, fp64 loss ----
    const float a0 = ws[0], a1 = ws[1], a2 = ws[2], a3 = ws[3];
    double l0 = 0.0, l1 = 0.0, l2 = 0.0, l3 = 0.0;
#pragma unroll 4
    for (int r = 0; r < RPB; ++r) {
        const float xv = x[(rowbase + r) * D + tid];
        const int i0 = kfin[0][r], i1 = kfin[1][r], i2 = kfin[2][r], i3 = kfin[3][r];
        float q0, q1, q2, q3;
        if (dT != nullptr) {
            q0 = dT[(size_t)i0 * D + tid];
            q1 = dT[(size_t)i1 * D + tid];
            q2 = dT[(size_t)i2 * D + tid];
            q3 = dT[(size_t)i3 * D + tid];
        } else {
            q0 = dget(bfr, i0, tid);
            q1 = dget(bfr, i1, tid);
            q2 = dget(bfr, i2, tid);
            q3 = dget(bfr, i3, tid);
        }
        float wq = __fadd_rn(__fadd_rn(__fadd_rn(__fmul_rn(a0, q0), __fmul_rn(a1, q1)),
                                       __fmul_rn(a2, q2)), __fmul_rn(a3, q3));
        out[(rowbase + r) * D + tid] = __fadd_rn(xv, __fsub_rn(wq, xv));
        const float e0 = xv - q0, e1 = xv - q1, e2 = xv - q2, e3 = xv - q3;
        l0 = fma((double)e0, (double)e0, l0);
        l1 = fma((double)e1, (double)e1, l1);
        l2 = fma((double)e2, (double)e2, l2);
        l3 = fma((double)e3, (double)e3, l3);
    }
#pragma unroll
    for (int off = 32; off; off >>= 1) {
        l0 += __shfl_down(l0, off); l1 += __shfl_down(l1, off);
        l2 += __shfl_down(l2, off); l3 += __shfl_down(l3, off);
    }
    if (lane == 0) { lred[wv][0] = l0; lred[wv][1] = l1; lred[wv][2] = l2; lred[wv][3] = l3; }
    __syncthreads();
    if (tid == 0) {
        double* lacc = (double*)(ws + 968);
#pragma unroll
        for (int i = 0; i < 4; ++i)
            atomicAdd(lacc + i, lred[0][i] + lred[1][i] + lred[2][i] + lred[3][i]);
    }
}

__global__ void vq_fin(const float* __restrict__ ws, float* __restrict__ out)
{
    if (threadIdx.x == 0) {
        const double* lacc = (const double*)(ws + 968);
        const double* dal  = (const double*)(ws + 976);
        double s = 0.0;
#pragma unroll
        for (int i = 0; i < 4; ++i) s += (lacc[i] * (1.0 / 16777216.0)) * dal[i];
        out[16777216] = (float)(s + 0.25 * s);
    }
}

extern "C" void kernel_launch(void* const* d_in, const int* in_sizes, int n_in,
                              void* d_out, int out_size, void* d_ws, size_t ws_size,
                              hipStream_t stream)
{
    const float* x   = (const float*)d_in[0];
    const float* av  = (const float*)d_in[1];
    const float* dc0 = (const float*)d_in[2];
    const float* dc1 = (const float*)d_in[3];
    const float* dc2 = (const float*)d_in[4];
    const float* dc3 = (const float*)d_in[5];
    float* out = (float*)d_out;
    float* ws  = (float*)d_ws;

    // plain fp32 dicT copy needs ws to hold 246784 + 960*256 floats
    const bool haveDT = ws_size >= (size_t)(WSDT + 960 * 256) * sizeof(float);
    float* dT = haveDT ? (ws + WSDT) : nullptr;

    hipLaunchKernelGGL(vq_prep, dim3(30), dim3(256), 0, stream, av, dc0, dc1, dc2, dc3, ws, dT);
    hipLaunchKernelGGL(vq_main, dim3(NROWS / RPB), dim3(256), 0, stream,
                       x, dc0, dc1, dc2, dc3, ws, dT, out);
    hipLaunchKernelGGL(vq_fin, dim3(1), dim3(64), 0, stream, ws, out);
}